// Round 5
// baseline (196.474 us; speedup 1.0000x reference)
//
#include <hip/hip_runtime.h>
#include <hip/hip_fp16.h>

// LatticeMultiHeadAttention — B=2, L=2048, D=1024, H=16, DK=64.
//
// Phase/bias computation skipped (exact): per-head constant bias cancels in
// softmax; masked scores (-10000) underflow to 0 regardless of bias.
//
// Round 5: attn processes 32 q-rows/wave (128/block) so every K/V LDS
// fragment read feeds two q-subtiles (halves LDS+staging cost per q).
// W pre-converted to f16 once (QSCALE folded into Wq) so qkv staging has
// zero f32->f16 converts on the B side and cvt_pkrtz pairs on the A side.

#define B_ 2
#define L_ 2048
#define D_ 1024
#define H_ 16
#define DK_ 64

// 0.125 * log2(e): folded into Wq at conversion; softmax in exp2 domain.
#define QSCALE 0.1803368801111244f
#define MASKOFF -14427.0f

typedef _Float16 f16;
typedef _Float16 f16x2 __attribute__((ext_vector_type(2)));
typedef _Float16 f16x4 __attribute__((ext_vector_type(4)));
typedef _Float16 f16x8 __attribute__((ext_vector_type(8)));
typedef __fp16 hf16x2 __attribute__((ext_vector_type(2)));
typedef float f32x4 __attribute__((ext_vector_type(4)));

// ---------------------------------------------------------------------------
// W converter: Wq (scaled by QSCALE), Wk, Wv -> f16, contiguous [3][1024][1024].
// ---------------------------------------------------------------------------
__global__ __launch_bounds__(256) void convw_kernel(
    const float* __restrict__ Wq, const float* __restrict__ Wk,
    const float* __restrict__ Wv, f16* __restrict__ Wf)
{
    const int z = blockIdx.y;
    const float* src = (z == 0) ? Wq : (z == 1) ? Wk : Wv;
    const float s = (z == 0) ? QSCALE : 1.0f;
    int i = (blockIdx.x * 256 + threadIdx.x) * 4;
    float4 v = *(const float4*)&src[i];
    hf16x2 h0 = __builtin_amdgcn_cvt_pkrtz(v.x * s, v.y * s);
    hf16x2 h1 = __builtin_amdgcn_cvt_pkrtz(v.z * s, v.w * s);
    f16x2 l0 = __builtin_bit_cast(f16x2, h0);
    f16x2 l1 = __builtin_bit_cast(f16x2, h1);
    f16x4 o; o[0] = l0[0]; o[1] = l0[1]; o[2] = l1[0]; o[3] = l1[1];
    *(f16x4*)&Wf[(size_t)z * 1048576 + i] = o;
}

// ---------------------------------------------------------------------------
// QKV projection GEMM (X f32 + W f16 in, f16 out). Q,K -> [b,h,l,k];
// V -> TRANSPOSED [b,h,k,l] so attn stages V^T with row-major b128 copies.
// ---------------------------------------------------------------------------
__global__ __launch_bounds__(256) void qkv_proj_kernel(
    const float* __restrict__ query, const float* __restrict__ keyx,
    const float* __restrict__ value, const f16* __restrict__ Wf,
    f16* __restrict__ Qh, f16* __restrict__ Kh, f16* __restrict__ VhT)
{
    const int z = blockIdx.z;
    const float* X = (z == 0) ? query : (z == 1) ? keyx : value;
    const f16* W = Wf + (size_t)z * 1048576;
    f16* out = (z == 0) ? Qh : (z == 1) ? Kh : VhT;

    const int m0 = blockIdx.x * 128;
    const int n0 = blockIdx.y * 128;
    const int tid = threadIdx.x;
    const int lane = tid & 63;
    const int w = tid >> 6;
    const int wr = (w >> 1) * 64, wc = (w & 1) * 64;

    __shared__ f16 As[128 * 40];
    __shared__ f16 Ws[128 * 40];

    f32x4 acc[4][4] = {};

    for (int kk = 0; kk < D_; kk += 32) {
        __syncthreads();
        {
            // A: f32 load + cvt_pkrtz (4 rows x 4 elems per thread)
            int r = tid >> 3, c = (tid & 7) * 4;
            #pragma unroll
            for (int p = 0; p < 4; ++p) {
                int row = p * 32 + r;
                float4 va = *(const float4*)&X[(size_t)(m0 + row) * D_ + kk + c];
                hf16x2 h0 = __builtin_amdgcn_cvt_pkrtz(va.x, va.y);
                hf16x2 h1 = __builtin_amdgcn_cvt_pkrtz(va.z, va.w);
                f16x2 l0 = __builtin_bit_cast(f16x2, h0);
                f16x2 l1 = __builtin_bit_cast(f16x2, h1);
                f16x4 ha; ha[0] = l0[0]; ha[1] = l0[1]; ha[2] = l1[0]; ha[3] = l1[1];
                *(f16x4*)&As[row * 40 + c] = ha;
            }
            // B: pure f16 copy (2 rows x 8 elems per thread)
            int rb = tid >> 2, cb = (tid & 3) * 8;
            #pragma unroll
            for (int p = 0; p < 2; ++p) {
                int row = p * 64 + rb;
                f16x8 vb = *(const f16x8*)&W[(size_t)(n0 + row) * D_ + kk + cb];
                *(f16x8*)&Ws[row * 40 + cb] = vb;
            }
        }
        __syncthreads();

        f16x8 af[4], bf[4];
        const int lg = (lane >> 4) * 8;
        #pragma unroll
        for (int i = 0; i < 4; ++i) {
            af[i] = *(const f16x8*)&As[(wr + i * 16 + (lane & 15)) * 40 + lg];
            bf[i] = *(const f16x8*)&Ws[(wc + i * 16 + (lane & 15)) * 40 + lg];
        }
        #pragma unroll
        for (int i = 0; i < 4; ++i)
            #pragma unroll
            for (int j = 0; j < 4; ++j)
                acc[i][j] = __builtin_amdgcn_mfma_f32_16x16x32_f16(af[i], bf[j], acc[i][j], 0, 0, 0);
    }

    if (z == 2) {
        // V^T epilogue: reg index r = 4 consecutive l at fixed dv -> f16x4.
        #pragma unroll
        for (int i = 0; i < 4; ++i) {
            int grow = m0 + wr + i * 16 + (lane >> 4) * 4;
            int b = grow >> 11, l = grow & (L_ - 1);
            #pragma unroll
            for (int j = 0; j < 4; ++j) {
                int gcol = n0 + wc + j * 16 + (lane & 15);
                int hh = gcol >> 6, k = gcol & 63;
                f16x4 o = { (f16)acc[i][j][0], (f16)acc[i][j][1],
                            (f16)acc[i][j][2], (f16)acc[i][j][3] };
                *(f16x4*)&out[((size_t)((b * H_ + hh) * DK_ + k)) * L_ + l] = o;
            }
        }
    } else {
        #pragma unroll
        for (int i = 0; i < 4; ++i) {
            int grow = m0 + wr + i * 16 + (lane >> 4) * 4;
            #pragma unroll
            for (int j = 0; j < 4; ++j) {
                int gcol = n0 + wc + j * 16 + (lane & 15);
                int hh = gcol >> 6, k = gcol & 63;
                #pragma unroll
                for (int r = 0; r < 4; ++r) {
                    int row = grow + r;
                    int b = row >> 11, l = row & (L_ - 1);
                    out[(((size_t)(b * H_ + hh)) * L_ + l) * DK_ + k] = (f16)acc[i][j][r];
                }
            }
        }
    }
}

// ---------------------------------------------------------------------------
// Flash attention. Block = 4 waves x 32 q rows = 128 q. Key tiles of 64.
// S^T = mfma(K, Q): lane holds q = lane&15 -> per-lane scalar softmax; two
// q-subtiles share every K/V fragment read. PV: O^T = mfma(V^T, P^T).
// ---------------------------------------------------------------------------
__global__ __launch_bounds__(256) void attn_kernel(
    const f16* __restrict__ Qh, const f16* __restrict__ Kh,
    const f16* __restrict__ VhT, const int* __restrict__ mask,
    f16* __restrict__ Oh)
{
    // XCD swizzle: the 16 q-blocks of a (b,h) land on the same XCD (id%8).
    const int n = blockIdx.x;                    // 512 blocks
    const int bh = ((n >> 7) << 3) + (n & 7);    // b*H + h
    const int qb = (n >> 3) & 15;
    const int b = bh >> 4, h = bh & 15;
    const int q0 = qb * 128;
    const int tid = threadIdx.x;
    const int lane = tid & 63;
    const int w = tid >> 6;
    const int lq = lane & 15, g = lane >> 4;

    __shared__ f16 Ks[64 * 72];
    __shared__ f16 Vt[64 * 72];
    __shared__ f16 Plds[4][32 * 72];
    __shared__ float mofft[64];

    const size_t base = (size_t)bh * L_ * DK_;
    const int* maskp = mask + b * L_;

    // Q fragments (B-operand) for two q-subtiles: q = q0 + w*32 + {lq, 16+lq}
    f16x8 qf0[2], qf1[2];
    {
        const f16* qptr = Qh + base + (size_t)(q0 + w * 32 + lq) * DK_ + g * 8;
        qf0[0] = *(const f16x8*)(qptr);
        qf0[1] = *(const f16x8*)(qptr + 32);
        qptr += 16 * DK_;
        qf1[0] = *(const f16x8*)(qptr);
        qf1[1] = *(const f16x8*)(qptr + 32);
    }

    const int srow = tid >> 2, scol = (tid & 3) * 16;   // staging map (K and V^T)

    f32x4 acc0[4] = {}, acc1[4] = {};  // O^T: dv = f*16 + g*4 + reg, q = lq (+16)
    float mrun0 = -1e30f, lrun0 = 0.f;
    float mrun1 = -1e30f, lrun1 = 0.f;

    f16x8 kA0, kA1, vA0, vA1;
    f16x8 kB0, kB1, vB0, vB1;

    auto issue = [&](int k0, f16x8& k0r, f16x8& k1r, f16x8& v0r, f16x8& v1r) {
        const f16* kp = Kh + base + (size_t)(k0 + srow) * DK_ + scol;
        k0r = *(const f16x8*)kp;
        k1r = *(const f16x8*)(kp + 8);
        const f16* vp = VhT + (size_t)(bh * DK_ + srow) * L_ + k0 + scol;
        v0r = *(const f16x8*)vp;
        v1r = *(const f16x8*)(vp + 8);
    };

    auto store_tile = [&](int k0, const f16x8& k0r, const f16x8& k1r,
                          const f16x8& v0r, const f16x8& v1r) {
        *(f16x8*)&Ks[srow * 72 + scol] = k0r;
        *(f16x8*)&Ks[srow * 72 + scol + 8] = k1r;
        *(f16x8*)&Vt[srow * 72 + scol] = v0r;
        *(f16x8*)&Vt[srow * 72 + scol + 8] = v1r;
        if (tid < 16) {
            int4 mv = *(const int4*)&maskp[k0 + tid * 4];
            float4 f = { mv.x ? 0.f : MASKOFF, mv.y ? 0.f : MASKOFF,
                         mv.z ? 0.f : MASKOFF, mv.w ? 0.f : MASKOFF };
            *(float4*)&mofft[tid * 4] = f;
        }
    };

    // softmax + P-pack/store for one q-subtile
    auto softmax_store = [&](float* sv, float& mrun, float& lrun,
                             f32x4* acc, int rowoff) {
        float a0 = fmaxf(sv[0], sv[1]),  a1 = fmaxf(sv[2], sv[3]);
        float a2 = fmaxf(sv[4], sv[5]),  a3 = fmaxf(sv[6], sv[7]);
        float a4 = fmaxf(sv[8], sv[9]),  a5 = fmaxf(sv[10], sv[11]);
        float a6 = fmaxf(sv[12], sv[13]), a7 = fmaxf(sv[14], sv[15]);
        float m = fmaxf(fmaxf(fmaxf(a0, a1), fmaxf(a2, a3)),
                        fmaxf(fmaxf(a4, a5), fmaxf(a6, a7)));
        m = fmaxf(m, __shfl_xor(m, 16, 64));
        m = fmaxf(m, __shfl_xor(m, 32, 64));
        if (__any(m > mrun)) {       // exact defer-max
            float mn = fmaxf(mrun, m);
            float scl = exp2f(mrun - mn);
            mrun = mn;
            lrun *= scl;
            #pragma unroll
            for (int f = 0; f < 4; ++f) acc[f] *= scl;
        }
        f16* pl = (f16*)Plds[w];
        float ls0 = 0.f, ls1 = 0.f;
        #pragma unroll
        for (int kt = 0; kt < 4; ++kt) {
            float p0 = exp2f(sv[kt * 4 + 0] - mrun);
            float p1 = exp2f(sv[kt * 4 + 1] - mrun);
            float p2 = exp2f(sv[kt * 4 + 2] - mrun);
            float p3 = exp2f(sv[kt * 4 + 3] - mrun);
            ls0 += p0 + p1;
            ls1 += p2 + p3;
            hf16x2 lo = __builtin_amdgcn_cvt_pkrtz(p0, p1);
            hf16x2 hi = __builtin_amdgcn_cvt_pkrtz(p2, p3);
            f16x2 lo2 = __builtin_bit_cast(f16x2, lo);
            f16x2 hi2 = __builtin_bit_cast(f16x2, hi);
            f16x4 pk; pk[0] = lo2[0]; pk[1] = lo2[1]; pk[2] = hi2[0]; pk[3] = hi2[1];
            *(f16x4*)&pl[(rowoff + lq) * 72 + kt * 16 + g * 4] = pk;
        }
        float ls = ls0 + ls1;
        ls += __shfl_xor(ls, 16, 64);
        ls += __shfl_xor(ls, 32, 64);
        lrun += ls;
    };

    auto compute = [&]() {
        float sv0[16], sv1[16];
        __builtin_amdgcn_s_setprio(1);
        #pragma unroll
        for (int kt = 0; kt < 4; ++kt) {
            f32x4 c = *(const f32x4*)&mofft[kt * 16 + g * 4];   // mask as C-in
            const f16* ka = &Ks[(kt * 16 + lq) * 72 + g * 8];
            f16x8 a0 = *(const f16x8*)ka;
            f16x8 a1 = *(const f16x8*)(ka + 32);
            f32x4 s0 = __builtin_amdgcn_mfma_f32_16x16x32_f16(a0, qf0[0], c, 0, 0, 0);
            s0 = __builtin_amdgcn_mfma_f32_16x16x32_f16(a1, qf0[1], s0, 0, 0, 0);
            f32x4 s1 = __builtin_amdgcn_mfma_f32_16x16x32_f16(a0, qf1[0], c, 0, 0, 0);
            s1 = __builtin_amdgcn_mfma_f32_16x16x32_f16(a1, qf1[1], s1, 0, 0, 0);
            *(f32x4*)&sv0[kt * 4] = s0;
            *(f32x4*)&sv1[kt * 4] = s1;
        }
        __builtin_amdgcn_s_setprio(0);

        softmax_store(sv0, mrun0, lrun0, acc0, 0);
        softmax_store(sv1, mrun1, lrun1, acc1, 16);
        asm volatile("s_waitcnt lgkmcnt(0)" ::: "memory");  // P-store -> PV-read RAW

        f16* pl = (f16*)Plds[w];
        __builtin_amdgcn_s_setprio(1);
        #pragma unroll
        for (int kc = 0; kc < 2; ++kc) {
            f16x8 pb0 = *(const f16x8*)&pl[lq * 72 + kc * 32 + g * 8];
            f16x8 pb1 = *(const f16x8*)&pl[(16 + lq) * 72 + kc * 32 + g * 8];
            #pragma unroll
            for (int f = 0; f < 4; ++f) {
                f16x8 va = *(const f16x8*)&Vt[(f * 16 + lq) * 72 + kc * 32 + g * 8];
                acc0[f] = __builtin_amdgcn_mfma_f32_16x16x32_f16(va, pb0, acc0[f], 0, 0, 0);
                acc1[f] = __builtin_amdgcn_mfma_f32_16x16x32_f16(va, pb1, acc1[f], 0, 0, 0);
            }
        }
        __builtin_amdgcn_s_setprio(0);
    };

    issue(0, kA0, kA1, vA0, vA1);
    for (int k0 = 0; k0 < L_; k0 += 128) {
        __syncthreads();
        store_tile(k0, kA0, kA1, vA0, vA1);
        issue(k0 + 64, kB0, kB1, vB0, vB1);
        __syncthreads();
        compute();

        __syncthreads();
        store_tile(k0 + 64, kB0, kB1, vB0, vB1);
        if (k0 + 128 < L_) issue(k0 + 128, kA0, kA1, vA0, vA1);
        __syncthreads();
        compute();
    }

    // epilogue: normalize and store O[q][dv] as f16x4 (both subtiles)
    {
        float inv = 1.f / lrun0;
        int q = q0 + w * 32 + lq;
        #pragma unroll
        for (int f = 0; f < 4; ++f) {
            f16x4 o = { (f16)(acc0[f][0] * inv), (f16)(acc0[f][1] * inv),
                        (f16)(acc0[f][2] * inv), (f16)(acc0[f][3] * inv) };
            *(f16x4*)&Oh[((size_t)(b * L_ + q)) * D_ + h * 64 + f * 16 + g * 4] = o;
        }
    }
    {
        float inv = 1.f / lrun1;
        int q = q0 + w * 32 + 16 + lq;
        #pragma unroll
        for (int f = 0; f < 4; ++f) {
            f16x4 o = { (f16)(acc1[f][0] * inv), (f16)(acc1[f][1] * inv),
                        (f16)(acc1[f][2] * inv), (f16)(acc1[f][3] * inv) };
            *(f16x4*)&Oh[((size_t)(b * L_ + q)) * D_ + h * 64 + f * 16 + g * 4] = o;
        }
    }
}

// ---------------------------------------------------------------------------
// Output projection GEMM (+bias), f32 out.
// ---------------------------------------------------------------------------
__global__ __launch_bounds__(256) void out_proj_kernel(
    const f16* __restrict__ Oh, const float* __restrict__ outw,
    const float* __restrict__ outb, float* __restrict__ Y)
{
    const int m0 = blockIdx.x * 128;
    const int n0 = blockIdx.y * 128;
    const int tid = threadIdx.x;
    const int lane = tid & 63;
    const int w = tid >> 6;
    const int wr = (w >> 1) * 64, wc = (w & 1) * 64;

    __shared__ f16 As[128 * 40];
    __shared__ f16 Ws[128 * 40];

    f32x4 acc[4][4] = {};

    for (int kk = 0; kk < D_; kk += 32) {
        __syncthreads();
        {
            int r = tid >> 3, c = (tid & 7) * 4;
            #pragma unroll
            for (int p = 0; p < 4; ++p) {
                int row = p * 32 + r;
                f16x4 ha = *(const f16x4*)&Oh[(size_t)(m0 + row) * D_ + kk + c];
                *(f16x4*)&As[row * 40 + c] = ha;
                float4 vb = *(const float4*)&outw[(size_t)(n0 + row) * D_ + kk + c];
                hf16x2 h0 = __builtin_amdgcn_cvt_pkrtz(vb.x, vb.y);
                hf16x2 h1 = __builtin_amdgcn_cvt_pkrtz(vb.z, vb.w);
                f16x2 l0 = __builtin_bit_cast(f16x2, h0);
                f16x2 l1 = __builtin_bit_cast(f16x2, h1);
                f16x4 hb; hb[0] = l0[0]; hb[1] = l0[1]; hb[2] = l1[0]; hb[3] = l1[1];
                *(f16x4*)&Ws[row * 40 + c] = hb;
            }
        }
        __syncthreads();

        f16x8 af[4], bf[4];
        const int lg = (lane >> 4) * 8;
        #pragma unroll
        for (int i = 0; i < 4; ++i) {
            af[i] = *(const f16x8*)&As[(wr + i * 16 + (lane & 15)) * 40 + lg];
            bf[i] = *(const f16x8*)&Ws[(wc + i * 16 + (lane & 15)) * 40 + lg];
        }
        #pragma unroll
        for (int i = 0; i < 4; ++i)
            #pragma unroll
            for (int j = 0; j < 4; ++j)
                acc[i][j] = __builtin_amdgcn_mfma_f32_16x16x32_f16(af[i], bf[j], acc[i][j], 0, 0, 0);
    }

    #pragma unroll
    for (int i = 0; i < 4; ++i) {
        int grow = m0 + wr + i * 16 + (lane >> 4) * 4;
        #pragma unroll
        for (int j = 0; j < 4; ++j) {
            int gcol = n0 + wc + j * 16 + (lane & 15);
            float bias = outb[gcol];
            #pragma unroll
            for (int r = 0; r < 4; ++r)
                Y[(size_t)(grow + r) * D_ + gcol] = acc[i][j][r] + bias;
        }
    }
}

extern "C" void kernel_launch(void* const* d_in, const int* in_sizes, int n_in,
                              void* d_out, int out_size, void* d_ws, size_t ws_size,
                              hipStream_t stream) {
    const float* query = (const float*)d_in[0];
    const float* key   = (const float*)d_in[1];
    const float* value = (const float*)d_in[2];
    const float* Wq    = (const float*)d_in[3];
    const float* Wk    = (const float*)d_in[4];
    const float* Wv    = (const float*)d_in[5];
    const float* outw  = (const float*)d_in[7];
    const float* outb  = (const float*)d_in[8];
    const int*   mask  = (const int*)d_in[10];
    float* Y = (float*)d_out;

    char* ws = (char*)d_ws;
    f16* Qh  = (f16*)(ws);                 // [0,8M):  [b,h,l,k] f16 (pre-scaled)
    f16* Kh  = (f16*)(ws + 8388608);       // [8,16M): [b,h,l,k]
    f16* VhT = (f16*)(ws + 16777216);      // [16,24M): [b,h,k,l] (V transposed)
    f16* Wf  = (f16*)(ws + 25165824);      // [24,30M): Wq|Wk|Wv f16 (dead after qkv)
    f16* Oh  = (f16*)(ws + 25165824);      // [24,32M): [b,l,h*64+k] (attn overwrites Wf)

    convw_kernel<<<dim3(1024, 3), 256, 0, stream>>>(Wq, Wk, Wv, Wf);
    qkv_proj_kernel<<<dim3(32, 8, 3), 256, 0, stream>>>(query, key, value,
                                                        Wf, Qh, Kh, VhT);
    attn_kernel<<<dim3(512), 256, 0, stream>>>(Qh, Kh, VhT, mask, Oh);
    out_proj_kernel<<<dim3(32, 8), 256, 0, stream>>>(Oh, outw, outb, Y);
}

// Round 6
// 179.936 us; speedup vs baseline: 1.0919x; 1.0919x over previous
//
#include <hip/hip_runtime.h>
#include <hip/hip_fp16.h>

// LatticeMultiHeadAttention — B=2, L=2048, D=1024, H=16, DK=64.
//
// Phase/bias computation skipped (exact): per-head constant bias cancels in
// softmax; masked scores (-10000) underflow to 0 regardless of bias.
//
// Round 6: qkv_proj reverted to round-4 form (f32 W staging; the r5
// f16-W/convw path regressed ~55->96us for unclear reasons — clean A/B).
// attn keeps round-5 structure (32 q/wave, mask-as-C-in, defer-max) plus
// a sched_barrier(0) after the asm lgkmcnt (rule #18).

#define B_ 2
#define L_ 2048
#define D_ 1024
#define H_ 16
#define DK_ 64

// 0.125 * log2(e): QK^T scale folded into Q projection, softmax in exp2 domain.
#define QSCALE 0.1803368801111244f
#define MASKOFF -14427.0f

typedef _Float16 f16;
typedef _Float16 f16x2 __attribute__((ext_vector_type(2)));
typedef _Float16 f16x4 __attribute__((ext_vector_type(4)));
typedef _Float16 f16x8 __attribute__((ext_vector_type(8)));
typedef __fp16 hf16x2 __attribute__((ext_vector_type(2)));
typedef float f32x4 __attribute__((ext_vector_type(4)));

// ---------------------------------------------------------------------------
// QKV projection GEMM (f32 in, f16 out). Q,K scattered to [b,h,l,k];
// V written TRANSPOSED to [b,h,k,l] (vectorized f16x4 stores) so the attn
// kernel can stage V^T with plain row-major b128 copies.
// ---------------------------------------------------------------------------
__global__ __launch_bounds__(256) void qkv_proj_kernel(
    const float* __restrict__ query, const float* __restrict__ keyx,
    const float* __restrict__ value,
    const float* __restrict__ Wq, const float* __restrict__ Wk,
    const float* __restrict__ Wv,
    f16* __restrict__ Qh, f16* __restrict__ Kh, f16* __restrict__ VhT)
{
    const int z = blockIdx.z;
    const float* X = (z == 0) ? query : (z == 1) ? keyx : value;
    const float* W = (z == 0) ? Wq : (z == 1) ? Wk : Wv;
    f16* out = (z == 0) ? Qh : (z == 1) ? Kh : VhT;
    const float qs = (z == 0) ? QSCALE : 1.0f;

    const int m0 = blockIdx.x * 128;
    const int n0 = blockIdx.y * 128;
    const int tid = threadIdx.x;
    const int lane = tid & 63;
    const int w = tid >> 6;
    const int wr = (w >> 1) * 64, wc = (w & 1) * 64;

    __shared__ f16 As[128 * 40];
    __shared__ f16 Ws[128 * 40];

    f32x4 acc[4][4] = {};

    for (int kk = 0; kk < D_; kk += 32) {
        __syncthreads();
        {
            int r = tid >> 3;
            int c = (tid & 7) * 4;
            #pragma unroll
            for (int p = 0; p < 4; ++p) {
                int row = p * 32 + r;
                float4 va = *(const float4*)&X[(size_t)(m0 + row) * D_ + kk + c];
                f16x4 ha = { (f16)(va.x * qs), (f16)(va.y * qs), (f16)(va.z * qs), (f16)(va.w * qs) };
                *(f16x4*)&As[row * 40 + c] = ha;
                float4 vb = *(const float4*)&W[(size_t)(n0 + row) * D_ + kk + c];
                f16x4 hb = { (f16)vb.x, (f16)vb.y, (f16)vb.z, (f16)vb.w };
                *(f16x4*)&Ws[row * 40 + c] = hb;
            }
        }
        __syncthreads();

        f16x8 af[4], bf[4];
        const int lg = (lane >> 4) * 8;
        #pragma unroll
        for (int i = 0; i < 4; ++i) {
            af[i] = *(const f16x8*)&As[(wr + i * 16 + (lane & 15)) * 40 + lg];
            bf[i] = *(const f16x8*)&Ws[(wc + i * 16 + (lane & 15)) * 40 + lg];
        }
        #pragma unroll
        for (int i = 0; i < 4; ++i)
            #pragma unroll
            for (int j = 0; j < 4; ++j)
                acc[i][j] = __builtin_amdgcn_mfma_f32_16x16x32_f16(af[i], bf[j], acc[i][j], 0, 0, 0);
    }

    if (z == 2) {
        // V^T epilogue: reg index r = 4 consecutive l at fixed dv -> f16x4.
        #pragma unroll
        for (int i = 0; i < 4; ++i) {
            int grow = m0 + wr + i * 16 + (lane >> 4) * 4;
            int b = grow >> 11, l = grow & (L_ - 1);
            #pragma unroll
            for (int j = 0; j < 4; ++j) {
                int gcol = n0 + wc + j * 16 + (lane & 15);
                int hh = gcol >> 6, k = gcol & 63;
                f16x4 o = { (f16)acc[i][j][0], (f16)acc[i][j][1],
                            (f16)acc[i][j][2], (f16)acc[i][j][3] };
                *(f16x4*)&out[((size_t)((b * H_ + hh) * DK_ + k)) * L_ + l] = o;
            }
        }
    } else {
        #pragma unroll
        for (int i = 0; i < 4; ++i) {
            int grow = m0 + wr + i * 16 + (lane >> 4) * 4;
            #pragma unroll
            for (int j = 0; j < 4; ++j) {
                int gcol = n0 + wc + j * 16 + (lane & 15);
                int hh = gcol >> 6, k = gcol & 63;
                #pragma unroll
                for (int r = 0; r < 4; ++r) {
                    int row = grow + r;
                    int b = row >> 11, l = row & (L_ - 1);
                    out[(((size_t)(b * H_ + hh)) * L_ + l) * DK_ + k] = (f16)acc[i][j][r];
                }
            }
        }
    }
}

// ---------------------------------------------------------------------------
// Flash attention. Block = 4 waves x 32 q rows = 128 q. Key tiles of 64.
// S^T = mfma(K, Q): lane holds q = lane&15 -> per-lane scalar softmax; two
// q-subtiles share every K/V fragment read. PV: O^T = mfma(V^T, P^T).
// ---------------------------------------------------------------------------
__global__ __launch_bounds__(256) void attn_kernel(
    const f16* __restrict__ Qh, const f16* __restrict__ Kh,
    const f16* __restrict__ VhT, const int* __restrict__ mask,
    f16* __restrict__ Oh)
{
    // XCD swizzle: the 16 q-blocks of a (b,h) land on the same XCD (id%8).
    const int n = blockIdx.x;                    // 512 blocks
    const int bh = ((n >> 7) << 3) + (n & 7);    // b*H + h
    const int qb = (n >> 3) & 15;
    const int b = bh >> 4, h = bh & 15;
    const int q0 = qb * 128;
    const int tid = threadIdx.x;
    const int lane = tid & 63;
    const int w = tid >> 6;
    const int lq = lane & 15, g = lane >> 4;

    __shared__ f16 Ks[64 * 72];
    __shared__ f16 Vt[64 * 72];
    __shared__ f16 Plds[4][32 * 72];
    __shared__ float mofft[64];

    const size_t base = (size_t)bh * L_ * DK_;
    const int* maskp = mask + b * L_;

    // Q fragments (B-operand) for two q-subtiles: q = q0 + w*32 + {lq, 16+lq}
    f16x8 qf0[2], qf1[2];
    {
        const f16* qptr = Qh + base + (size_t)(q0 + w * 32 + lq) * DK_ + g * 8;
        qf0[0] = *(const f16x8*)(qptr);
        qf0[1] = *(const f16x8*)(qptr + 32);
        qptr += 16 * DK_;
        qf1[0] = *(const f16x8*)(qptr);
        qf1[1] = *(const f16x8*)(qptr + 32);
    }

    const int srow = tid >> 2, scol = (tid & 3) * 16;   // staging map (K and V^T)

    f32x4 acc0[4] = {}, acc1[4] = {};  // O^T: dv = f*16 + g*4 + reg, q = lq (+16)
    float mrun0 = -1e30f, lrun0 = 0.f;
    float mrun1 = -1e30f, lrun1 = 0.f;

    f16x8 kA0, kA1, vA0, vA1;
    f16x8 kB0, kB1, vB0, vB1;

    auto issue = [&](int k0, f16x8& k0r, f16x8& k1r, f16x8& v0r, f16x8& v1r) {
        const f16* kp = Kh + base + (size_t)(k0 + srow) * DK_ + scol;
        k0r = *(const f16x8*)kp;
        k1r = *(const f16x8*)(kp + 8);
        const f16* vp = VhT + (size_t)(bh * DK_ + srow) * L_ + k0 + scol;
        v0r = *(const f16x8*)vp;
        v1r = *(const f16x8*)(vp + 8);
    };

    auto store_tile = [&](int k0, const f16x8& k0r, const f16x8& k1r,
                          const f16x8& v0r, const f16x8& v1r) {
        *(f16x8*)&Ks[srow * 72 + scol] = k0r;
        *(f16x8*)&Ks[srow * 72 + scol + 8] = k1r;
        *(f16x8*)&Vt[srow * 72 + scol] = v0r;
        *(f16x8*)&Vt[srow * 72 + scol + 8] = v1r;
        if (tid < 16) {
            int4 mv = *(const int4*)&maskp[k0 + tid * 4];
            float4 f = { mv.x ? 0.f : MASKOFF, mv.y ? 0.f : MASKOFF,
                         mv.z ? 0.f : MASKOFF, mv.w ? 0.f : MASKOFF };
            *(float4*)&mofft[tid * 4] = f;
        }
    };

    // softmax + P-pack/store for one q-subtile
    auto softmax_store = [&](float* sv, float& mrun, float& lrun,
                             f32x4* acc, int rowoff) {
        float a0 = fmaxf(sv[0], sv[1]),  a1 = fmaxf(sv[2], sv[3]);
        float a2 = fmaxf(sv[4], sv[5]),  a3 = fmaxf(sv[6], sv[7]);
        float a4 = fmaxf(sv[8], sv[9]),  a5 = fmaxf(sv[10], sv[11]);
        float a6 = fmaxf(sv[12], sv[13]), a7 = fmaxf(sv[14], sv[15]);
        float m = fmaxf(fmaxf(fmaxf(a0, a1), fmaxf(a2, a3)),
                        fmaxf(fmaxf(a4, a5), fmaxf(a6, a7)));
        m = fmaxf(m, __shfl_xor(m, 16, 64));
        m = fmaxf(m, __shfl_xor(m, 32, 64));
        if (__any(m > mrun)) {       // exact defer-max
            float mn = fmaxf(mrun, m);
            float scl = exp2f(mrun - mn);
            mrun = mn;
            lrun *= scl;
            #pragma unroll
            for (int f = 0; f < 4; ++f) acc[f] *= scl;
        }
        f16* pl = (f16*)Plds[w];
        float ls0 = 0.f, ls1 = 0.f;
        #pragma unroll
        for (int kt = 0; kt < 4; ++kt) {
            float p0 = exp2f(sv[kt * 4 + 0] - mrun);
            float p1 = exp2f(sv[kt * 4 + 1] - mrun);
            float p2 = exp2f(sv[kt * 4 + 2] - mrun);
            float p3 = exp2f(sv[kt * 4 + 3] - mrun);
            ls0 += p0 + p1;
            ls1 += p2 + p3;
            hf16x2 lo = __builtin_amdgcn_cvt_pkrtz(p0, p1);
            hf16x2 hi = __builtin_amdgcn_cvt_pkrtz(p2, p3);
            f16x2 lo2 = __builtin_bit_cast(f16x2, lo);
            f16x2 hi2 = __builtin_bit_cast(f16x2, hi);
            f16x4 pk; pk[0] = lo2[0]; pk[1] = lo2[1]; pk[2] = hi2[0]; pk[3] = hi2[1];
            *(f16x4*)&pl[(rowoff + lq) * 72 + kt * 16 + g * 4] = pk;
        }
        float ls = ls0 + ls1;
        ls += __shfl_xor(ls, 16, 64);
        ls += __shfl_xor(ls, 32, 64);
        lrun += ls;
    };

    auto compute = [&]() {
        float sv0[16], sv1[16];
        __builtin_amdgcn_s_setprio(1);
        #pragma unroll
        for (int kt = 0; kt < 4; ++kt) {
            f32x4 c = *(const f32x4*)&mofft[kt * 16 + g * 4];   // mask as C-in
            const f16* ka = &Ks[(kt * 16 + lq) * 72 + g * 8];
            f16x8 a0 = *(const f16x8*)ka;
            f16x8 a1 = *(const f16x8*)(ka + 32);
            f32x4 s0 = __builtin_amdgcn_mfma_f32_16x16x32_f16(a0, qf0[0], c, 0, 0, 0);
            s0 = __builtin_amdgcn_mfma_f32_16x16x32_f16(a1, qf0[1], s0, 0, 0, 0);
            f32x4 s1 = __builtin_amdgcn_mfma_f32_16x16x32_f16(a0, qf1[0], c, 0, 0, 0);
            s1 = __builtin_amdgcn_mfma_f32_16x16x32_f16(a1, qf1[1], s1, 0, 0, 0);
            *(f32x4*)&sv0[kt * 4] = s0;
            *(f32x4*)&sv1[kt * 4] = s1;
        }
        __builtin_amdgcn_s_setprio(0);

        softmax_store(sv0, mrun0, lrun0, acc0, 0);
        softmax_store(sv1, mrun1, lrun1, acc1, 16);
        asm volatile("s_waitcnt lgkmcnt(0)" ::: "memory");  // P-store -> PV-read RAW
        __builtin_amdgcn_sched_barrier(0);                  // rule #18 fence

        f16* pl = (f16*)Plds[w];
        __builtin_amdgcn_s_setprio(1);
        #pragma unroll
        for (int kc = 0; kc < 2; ++kc) {
            f16x8 pb0 = *(const f16x8*)&pl[lq * 72 + kc * 32 + g * 8];
            f16x8 pb1 = *(const f16x8*)&pl[(16 + lq) * 72 + kc * 32 + g * 8];
            #pragma unroll
            for (int f = 0; f < 4; ++f) {
                f16x8 va = *(const f16x8*)&Vt[(f * 16 + lq) * 72 + kc * 32 + g * 8];
                acc0[f] = __builtin_amdgcn_mfma_f32_16x16x32_f16(va, pb0, acc0[f], 0, 0, 0);
                acc1[f] = __builtin_amdgcn_mfma_f32_16x16x32_f16(va, pb1, acc1[f], 0, 0, 0);
            }
        }
        __builtin_amdgcn_s_setprio(0);
    };

    issue(0, kA0, kA1, vA0, vA1);
    for (int k0 = 0; k0 < L_; k0 += 128) {
        __syncthreads();
        store_tile(k0, kA0, kA1, vA0, vA1);
        issue(k0 + 64, kB0, kB1, vB0, vB1);
        __syncthreads();
        compute();

        __syncthreads();
        store_tile(k0 + 64, kB0, kB1, vB0, vB1);
        if (k0 + 128 < L_) issue(k0 + 128, kA0, kA1, vA0, vA1);
        __syncthreads();
        compute();
    }

    // epilogue: normalize and store O[q][dv] as f16x4 (both subtiles)
    {
        float inv = 1.f / lrun0;
        int q = q0 + w * 32 + lq;
        #pragma unroll
        for (int f = 0; f < 4; ++f) {
            f16x4 o = { (f16)(acc0[f][0] * inv), (f16)(acc0[f][1] * inv),
                        (f16)(acc0[f][2] * inv), (f16)(acc0[f][3] * inv) };
            *(f16x4*)&Oh[((size_t)(b * L_ + q)) * D_ + h * 64 + f * 16 + g * 4] = o;
        }
    }
    {
        float inv = 1.f / lrun1;
        int q = q0 + w * 32 + 16 + lq;
        #pragma unroll
        for (int f = 0; f < 4; ++f) {
            f16x4 o = { (f16)(acc1[f][0] * inv), (f16)(acc1[f][1] * inv),
                        (f16)(acc1[f][2] * inv), (f16)(acc1[f][3] * inv) };
            *(f16x4*)&Oh[((size_t)(b * L_ + q)) * D_ + h * 64 + f * 16 + g * 4] = o;
        }
    }
}

// ---------------------------------------------------------------------------
// Output projection GEMM (+bias), f32 out.
// ---------------------------------------------------------------------------
__global__ __launch_bounds__(256) void out_proj_kernel(
    const f16* __restrict__ Oh, const float* __restrict__ outw,
    const float* __restrict__ outb, float* __restrict__ Y)
{
    const int m0 = blockIdx.x * 128;
    const int n0 = blockIdx.y * 128;
    const int tid = threadIdx.x;
    const int lane = tid & 63;
    const int w = tid >> 6;
    const int wr = (w >> 1) * 64, wc = (w & 1) * 64;

    __shared__ f16 As[128 * 40];
    __shared__ f16 Ws[128 * 40];

    f32x4 acc[4][4] = {};

    for (int kk = 0; kk < D_; kk += 32) {
        __syncthreads();
        {
            int r = tid >> 3;
            int c = (tid & 7) * 4;
            #pragma unroll
            for (int p = 0; p < 4; ++p) {
                int row = p * 32 + r;
                f16x4 ha = *(const f16x4*)&Oh[(size_t)(m0 + row) * D_ + kk + c];
                *(f16x4*)&As[row * 40 + c] = ha;
                float4 vb = *(const float4*)&outw[(size_t)(n0 + row) * D_ + kk + c];
                f16x4 hb = { (f16)vb.x, (f16)vb.y, (f16)vb.z, (f16)vb.w };
                *(f16x4*)&Ws[row * 40 + c] = hb;
            }
        }
        __syncthreads();

        f16x8 af[4], bf[4];
        const int lg = (lane >> 4) * 8;
        #pragma unroll
        for (int i = 0; i < 4; ++i) {
            af[i] = *(const f16x8*)&As[(wr + i * 16 + (lane & 15)) * 40 + lg];
            bf[i] = *(const f16x8*)&Ws[(wc + i * 16 + (lane & 15)) * 40 + lg];
        }
        #pragma unroll
        for (int i = 0; i < 4; ++i)
            #pragma unroll
            for (int j = 0; j < 4; ++j)
                acc[i][j] = __builtin_amdgcn_mfma_f32_16x16x32_f16(af[i], bf[j], acc[i][j], 0, 0, 0);
    }

    #pragma unroll
    for (int i = 0; i < 4; ++i) {
        int grow = m0 + wr + i * 16 + (lane >> 4) * 4;
        #pragma unroll
        for (int j = 0; j < 4; ++j) {
            int gcol = n0 + wc + j * 16 + (lane & 15);
            float bias = outb[gcol];
            #pragma unroll
            for (int r = 0; r < 4; ++r)
                Y[(size_t)(grow + r) * D_ + gcol] = acc[i][j][r] + bias;
        }
    }
}

extern "C" void kernel_launch(void* const* d_in, const int* in_sizes, int n_in,
                              void* d_out, int out_size, void* d_ws, size_t ws_size,
                              hipStream_t stream) {
    const float* query = (const float*)d_in[0];
    const float* key   = (const float*)d_in[1];
    const float* value = (const float*)d_in[2];
    const float* Wq    = (const float*)d_in[3];
    const float* Wk    = (const float*)d_in[4];
    const float* Wv    = (const float*)d_in[5];
    const float* outw  = (const float*)d_in[7];
    const float* outb  = (const float*)d_in[8];
    const int*   mask  = (const int*)d_in[10];
    float* Y = (float*)d_out;

    char* ws = (char*)d_ws;
    f16* Qh  = (f16*)(ws);                 //  8 MiB: [b,h,l,k] f16 (pre-scaled)
    f16* Kh  = (f16*)(ws + 8388608);       //  8 MiB: [b,h,l,k]
    f16* VhT = (f16*)(ws + 16777216);      //  8 MiB: [b,h,k,l]  (V transposed)
    f16* Oh  = (f16*)(ws + 25165824);      //  8 MiB: [b,l,h*64+k]

    qkv_proj_kernel<<<dim3(32, 8, 3), 256, 0, stream>>>(query, key, value,
                                                        Wq, Wk, Wv, Qh, Kh, VhT);
    attn_kernel<<<dim3(512), 256, 0, stream>>>(Qh, Kh, VhT, mask, Oh);
    out_proj_kernel<<<dim3(32, 8), 256, 0, stream>>>(Oh, outw, outb, Y);
}